// Round 6
// baseline (528.851 us; speedup 1.0000x reference)
//
#include <hip/hip_runtime.h>
#include <math.h>

// CRF forward partition scan. B=512, S=1024, T=48.
//
// R15: part broadcast via ds_bpermute. R14 (emission staged via
// global_load_lds, zero VMEM in loop) = 326us, VALUBusy 27.9% -> issue
// ~290 cyc/exec-step, stall ~790. Biggest discrete serial segment left:
// the part publish round trip (p_sh store -> fence -> 12 ds_read_b128)
// on the recurrence between consecutive executed steps. Fix: gather the
// 48 part values straight from lane VGPRs with 48 ds_bpermute_b32
// (shared addr reg = opaque zero, element index in the DS offset:
// immediate). No store, no fence, no RAW pipe dependency; p_sh deleted.
// All gather sites are wave-uniform (all 64 lanes active) -> bpermute
// safe; bits moved verbatim -> results bit-identical.
//  - emission staging per 64-step block via global_load_lds w16,
//    double-buffered, one vmcnt(0) drain per 64 steps (R14, proven).
//  - T column (TQ) + exp(T) (EV) in registers (R11+, proven).
//  - pass2 via readlane + scalar fma (R13, proven).

constexpr int kB  = 512;
constexpr int kS  = 1024;
constexpr int kT  = 48;

typedef float v2 __attribute__((ext_vector_type(2)));
struct V2P { v2 lo, hi; };

#define REP12(X) X(0) X(1) X(2) X(3) X(4) X(5) X(6) X(7) X(8) X(9) X(10) X(11)

// X(k, i0, i1): EV pair k covers transition rows i0=2k, i1=2k+1
#define REP24(X) \
  X(0,0,1)    X(1,2,3)    X(2,4,5)    X(3,6,7) \
  X(4,8,9)    X(5,10,11)  X(6,12,13)  X(7,14,15) \
  X(8,16,17)  X(9,18,19)  X(10,20,21) X(11,22,23) \
  X(12,24,25) X(13,26,27) X(14,28,29) X(15,30,31) \
  X(16,32,33) X(17,34,35) X(18,36,37) X(19,38,39) \
  X(20,40,41) X(21,42,43) X(22,44,45) X(23,46,47)

// X(q, evA, evB, a, b): quad q (rows 4q..4q+3), EV pair ids, acc ids
#define REPQ(X) \
  X(0,0,1,0,3)    X(1,2,3,1,2)    X(2,4,5,2,1)    X(3,6,7,3,0) \
  X(4,8,9,0,3)    X(5,10,11,1,2)  X(6,12,13,2,1)  X(7,14,15,3,0) \
  X(8,16,17,0,3)  X(9,18,19,1,2)  X(10,20,21,2,1) X(11,22,23,3,0)

// Transition column j, rows 4q..4q+3, held in registers for the whole kernel.
#define DECL_TQ(q)  float4 TQ##q;
#define INIT_TQ(q)  { TQ##q.x = trans[(4*(q)+0)*kT + j]; \
                      TQ##q.y = trans[(4*(q)+1)*kT + j]; \
                      TQ##q.z = trans[(4*(q)+2)*kT + j]; \
                      TQ##q.w = trans[(4*(q)+3)*kT + j]; }

#define DECL_EV(k,i0,i1)  v2 EV##k;
#define INIT_EV(k,i0,i1)  EV##k = (v2){__expf(trans[(i0)*kT + j]), \
                                       __expf(trans[(i1)*kT + j])};

// Gathered part vector in 12 float4 regs (48 VGPRs), refreshed by
// GATHERF after each part update: lane j pulls part from lane i via the
// LDS crossbar. bpz is an opaque zero VGPR (threadIdx.y) so the 4*i
// byte index folds into the DS offset: immediate -- one shared addr reg.
#define DECL_F(q)  float4 F##q;
#define BPF(i) __builtin_bit_cast(float, \
    __builtin_amdgcn_ds_bpermute(bpz + 4*(i), pbits))
#define GATHERF(q) { \
    F##q.x = BPF(4*(q)+0); F##q.y = BPF(4*(q)+1); \
    F##q.z = BPF(4*(q)+2); F##q.w = BPF(4*(q)+3); }

// Broadcast lane i's float to all lanes via v_readlane (SGPR result).
#define RLF(v, i) \
  __builtin_bit_cast(float, __builtin_amdgcn_readlane(__builtin_bit_cast(int, (v)), (i)))

// pass 1 (packed, on gathered F): mv[a]=max(mv[a],T.lo+p.lo); mv[b] .hi
#define PASS1(q,evA,evB,a,b) { \
    const V2P t_ = __builtin_bit_cast(V2P, TQ##q); \
    const V2P p_ = __builtin_bit_cast(V2P, F##q);  \
    mv##a = __builtin_elementwise_max(mv##a, t_.lo + p_.lo); \
    mv##b = __builtin_elementwise_max(mv##b, t_.hi + p_.hi); }

// pass 2 (scalar fma, ea via readlane SGPR operand). Accumulator mapping
// replicates the pk_fma version exactly -> bit-identical.
#define PASS2(q,evA,evB,a,b) { \
    const float qx_ = RLF(ea, 4*(q)+0); \
    const float qy_ = RLF(ea, 4*(q)+1); \
    const float qz_ = RLF(ea, 4*(q)+2); \
    const float qw_ = RLF(ea, 4*(q)+3); \
    sv##a##x = fmaf(EV##evA.x, qx_, sv##a##x); \
    sv##a##y = fmaf(EV##evA.y, qy_, sv##a##y); \
    sv##b##x = fmaf(EV##evB.x, qz_, sv##b##x); \
    sv##b##y = fmaf(EV##evB.y, qw_, sv##b##y); }

__global__ __launch_bounds__(64, 1) void crf_fwd(
    const float* __restrict__ feats,   // [B, S, T] fp32
    const int*   __restrict__ mask,    // [B, S] int32 (bool)
    const float* __restrict__ trans,   // [T, T] fp32
    float*       __restrict__ out)     // [1 + B]; we write out[1+b]
{
    const int b    = blockIdx.x;
    const int lane = threadIdx.x;
    const int j    = (lane < kT) ? lane : (kT - 1);  // clamp idle lanes
    const int bpz  = (int)threadIdx.y;  // opaque 0: shared bpermute addr base

    // Emission staging: 64 rows x 48 floats = 12KB per buffer, dbl-buffered.
    __shared__ alignas(16) float e_sh[2][64 * kT];

    const float* fbase = feats + (size_t)b * kS * kT;   // this chain's rows
    const int*   mb    = mask  + (size_t)b * kS;

    // Issue the first 64-row stage EARLY; latency hides under TQ/EV init.
    // 12 calls x (64 lanes x 16B) = 12KB = rows 0..63 (contiguous).
#define STAGE_E(BUFIDX, T0) \
    _Pragma("unroll") \
    for (int c_ = 0; c_ < 12; ++c_) { \
        __builtin_amdgcn_global_load_lds( \
            (const __attribute__((address_space(1))) unsigned int*) \
                (fbase + (size_t)(T0) * kT + c_ * 256 + lane * 4), \
            (__attribute__((address_space(3))) unsigned int*) \
                (&e_sh[BUFIDX][c_ * 256]), \
            16, 0, 0); \
    }

    STAGE_E(0, 0)

    // T column and E column in registers.
    REP12(DECL_TQ)
    REP12(INIT_TQ)
    REP24(DECL_EV)
    REP24(INIT_EV)
    REP12(DECL_F)

    // part0 = emit[0] + transition[T-2, :]   (row 46, column j)
    float part = fbase[j] + trans[(kT - 2) * kT + j];
    {   // initial gather of part into F (all lanes active)
        const int pbits = __builtin_bit_cast(int, part);
        REP12(GATHERF)
    }

    int mreg = mb[lane];   // mask words for steps 0..63 (coalesced)
    int buf  = 0;

    for (int blk = 0; blk < 16; ++blk) {
        // Drain staging: e_sh[buf] + mreg were issued ~64 steps ago (or at
        // init) -> this wait is effectively free.
        asm volatile("s_waitcnt vmcnt(0)" ::: "memory");

        // Uniform 64-step mask bitmask in an SGPR pair; per-step gate is
        // s_and/s_lshr + s_cbranch -- zero memory, zero VALU.
        unsigned long long bits = __ballot(mreg != 0);
        if (blk < 15) {
            mreg = mb[(blk + 1) * 64 + lane];   // next block's mask word
            STAGE_E(buf ^ 1, (blk + 1) * 64)    // next block's emission rows
        }
        int t = blk * 64;
        const int tend = t + 64;
        if (blk == 0) { bits >>= 1; t = 1; }  // scan starts at step 1

        for (; t < tend; ++t) {
            const bool mk = bits & 1ull;
            bits >>= 1;

            if (mk) {  // wave-uniform branch: skip masked-out steps
                // e from LDS; latency hides under pass1 (first use is ea).
                const float e = e_sh[buf][(t & 63) * kT + j];
                const float pe = part - e;  // off the M-critical path

                // pass 1 on gathered F: M_j = max_i (T[i,j] + part_i)
                v2 mv0 = {-INFINITY, -INFINITY};
                v2 mv1 = mv0, mv2 = mv0, mv3 = mv0;
                REPQ(PASS1)
                mv0 = __builtin_elementwise_max(mv0, mv1);
                mv2 = __builtin_elementwise_max(mv2, mv3);
                mv0 = __builtin_elementwise_max(mv0, mv2);
                const float M = fmaxf(mv0.x, mv0.y);

                // lane i holds ea_i = exp(part_i - e_i - M_i)
                const float ea = __expf(pe - M);

                // pass 2: S_j = sum_i exp(T[i,j]) * ea_i  (readlane + fma)
                float sv0x = 0.f, sv0y = 0.f, sv1x = 0.f, sv1y = 0.f;
                float sv2x = 0.f, sv2y = 0.f, sv3x = 0.f, sv3y = 0.f;
                REPQ(PASS2)
                sv0x += sv1x; sv0y += sv1y;
                sv2x += sv3x; sv2y += sv3y;
                sv0x += sv2x; sv0y += sv2y;
                const float Ssum = sv0x + sv0y;

                part = 2.0f * e + M + __logf(Ssum);

                // refresh gathered F from the new part (no store, no
                // fence); F stays valid across masked steps.
                const int pbits = __builtin_bit_cast(int, part);
                REP12(GATHERF)
            }
        }
        buf ^= 1;
    }

    // Final transition-only step; only end_value[:, T-1] is stored.
    // F regs hold the current gathered part (gather invariant).
    {
        v2 mv0 = {-INFINITY, -INFINITY};
        v2 mv1 = mv0, mv2 = mv0, mv3 = mv0;
        REPQ(PASS1)
        mv0 = __builtin_elementwise_max(mv0, mv1);
        mv2 = __builtin_elementwise_max(mv2, mv3);
        mv0 = __builtin_elementwise_max(mv0, mv2);
        const float M = fmaxf(mv0.x, mv0.y);
        const float ea = __expf(part - M);   // no emission in final step

        float sv0x = 0.f, sv0y = 0.f, sv1x = 0.f, sv1y = 0.f;
        float sv2x = 0.f, sv2y = 0.f, sv3x = 0.f, sv3y = 0.f;
        REPQ(PASS2)
        sv0x += sv1x; sv0y += sv1y;
        sv2x += sv3x; sv2y += sv3y;
        sv0x += sv2x; sv0y += sv2y;
        const float Ssum = sv0x + sv0y;
        const float val = M + __logf(Ssum);
        if (lane == kT - 1) out[1 + b] = val;  // score[b] = end_value[b,-1]
    }
}

// out[0] = sum(score). Single wave; no barriers needed.
__global__ __launch_bounds__(64) void sum_scores(
    const float* __restrict__ sc, float* __restrict__ out)
{
    float s = 0.f;
    for (int i = (int)threadIdx.x; i < kB; i += 64) s += sc[i];
#pragma unroll
    for (int off = 32; off > 0; off >>= 1) s += __shfl_down(s, off);
    if (threadIdx.x == 0) out[0] = s;
}

extern "C" void kernel_launch(void* const* d_in, const int* in_sizes, int n_in,
                              void* d_out, int out_size, void* d_ws, size_t ws_size,
                              hipStream_t stream) {
    const float* feats = (const float*)d_in[0];
    const int*   mask  = (const int*)d_in[1];
    const float* trans = (const float*)d_in[2];
    float*       out   = (float*)d_out;

    crf_fwd<<<dim3(kB), dim3(64), 0, stream>>>(feats, mask, trans, out);
    sum_scores<<<dim3(1), dim3(64), 0, stream>>>(out + 1, out);
}

// Round 7
// 388.669 us; speedup vs baseline: 1.3607x; 1.3607x over previous
//
#include <hip/hip_runtime.h>
#include <math.h>

// CRF forward partition scan. B=512, S=1024, T=48.
//
// R16: R14 chassis (staged emissions, zero VMEM in loop, p_sh part
// broadcast) + pass2 back to LDS ea-broadcast with PACKED fma.
// R15 post-mortem: 48 ds_bpermute >> 1 store + 12 b128 in LDS-pipe cost
// (-105us regression) -> reverted. R14 budget: 1090 cyc/exec-step =
// 305 issue + ~200 part-RT + ~60 exp/log + ~450 UNATTRIBUTED. Suspect:
// pass2's 48 v_readlane each incur a VALU->SGPR->VALU RAW hazard
// (~5-10cyc) at the dependent v_fma -> ~250-480 cyc/step, matching the
// hole (R13's VALUBusy drop 25.5->20.5 at flat time corroborates).
// Fix: publish ea to ea_sh, 12 ds_read_b128, 24 v_pk_fma (R10's proven
// pass2 mapping, bit-identical to the scalar form per R13). Removes
// readlanes+hazards+24 fma issue; adds one LDS RT partially behind exp.
//  - emission staging per 64-step block via global_load_lds w16,
//    double-buffered, one vmcnt(0) drain per 64 steps (R14, proven).
//  - T column (TQ) + exp(T) (EV) in registers (R11+, proven).

constexpr int kB  = 512;
constexpr int kS  = 1024;
constexpr int kT  = 48;

typedef float v2 __attribute__((ext_vector_type(2)));
struct V2P { v2 lo, hi; };

#define REP12(X) X(0) X(1) X(2) X(3) X(4) X(5) X(6) X(7) X(8) X(9) X(10) X(11)

// X(k, i0, i1): EV pair k covers transition rows i0=2k, i1=2k+1
#define REP24(X) \
  X(0,0,1)    X(1,2,3)    X(2,4,5)    X(3,6,7) \
  X(4,8,9)    X(5,10,11)  X(6,12,13)  X(7,14,15) \
  X(8,16,17)  X(9,18,19)  X(10,20,21) X(11,22,23) \
  X(12,24,25) X(13,26,27) X(14,28,29) X(15,30,31) \
  X(16,32,33) X(17,34,35) X(18,36,37) X(19,38,39) \
  X(20,40,41) X(21,42,43) X(22,44,45) X(23,46,47)

// X(q, evA, evB, a, b): quad q (rows 4q..4q+3), EV pair ids, acc ids
#define REPQ(X) \
  X(0,0,1,0,3)    X(1,2,3,1,2)    X(2,4,5,2,1)    X(3,6,7,3,0) \
  X(4,8,9,0,3)    X(5,10,11,1,2)  X(6,12,13,2,1)  X(7,14,15,3,0) \
  X(8,16,17,0,3)  X(9,18,19,1,2)  X(10,20,21,2,1) X(11,22,23,3,0)

// Transition column j, rows 4q..4q+3, held in registers for the whole kernel.
#define DECL_TQ(q)  float4 TQ##q;
#define INIT_TQ(q)  { TQ##q.x = trans[(4*(q)+0)*kT + j]; \
                      TQ##q.y = trans[(4*(q)+1)*kT + j]; \
                      TQ##q.z = trans[(4*(q)+2)*kT + j]; \
                      TQ##q.w = trans[(4*(q)+3)*kT + j]; }

#define DECL_EV(k,i0,i1)  v2 EV##k;
#define INIT_EV(k,i0,i1)  EV##k = (v2){__expf(trans[(i0)*kT + j]), \
                                       __expf(trans[(i1)*kT + j])};

// Gathered part vector, prefetched into 12 float4 regs (48 VGPRs).
#define DECL_F(q)  float4 F##q;
#define LOADF(q)   F##q = p4[q];

// Gathered ea vector (12 float4 reads from ea_sh).
#define LOADQ(q)   const float4 Q##q = q4[q];

// pass 1 (packed, on prefetched F): mv[a]=max(mv[a],T.lo+p.lo); mv[b] .hi
#define PASS1(q,evA,evB,a,b) { \
    const V2P t_ = __builtin_bit_cast(V2P, TQ##q); \
    const V2P p_ = __builtin_bit_cast(V2P, F##q);  \
    mv##a = __builtin_elementwise_max(mv##a, t_.lo + p_.lo); \
    mv##b = __builtin_elementwise_max(mv##b, t_.hi + p_.hi); }

// pass 2 (packed fma on gathered Q): sv[a] += EV[evA]*q.lo; sv[b] += .hi
#define PASS2(q,evA,evB,a,b) { \
    const V2P q_ = __builtin_bit_cast(V2P, Q##q); \
    sv##a = __builtin_elementwise_fma(EV##evA, q_.lo, sv##a); \
    sv##b = __builtin_elementwise_fma(EV##evB, q_.hi, sv##b); }

// Single-wave workgroup: LDS pipe is in-order per wave, so cross-lane RAW
// through LDS needs only a compiler scheduling fence, not s_barrier.
__device__ __forceinline__ void wave_fence() {
    __builtin_amdgcn_wave_barrier();
}

__global__ __launch_bounds__(64, 1) void crf_fwd(
    const float* __restrict__ feats,   // [B, S, T] fp32
    const int*   __restrict__ mask,    // [B, S] int32 (bool)
    const float* __restrict__ trans,   // [T, T] fp32
    float*       __restrict__ out)     // [1 + B]; we write out[1+b]
{
    const int b    = blockIdx.x;
    const int lane = threadIdx.x;
    const int j    = (lane < kT) ? lane : (kT - 1);  // clamp idle lanes

    // Emission staging: 64 rows x 48 floats = 12KB per buffer, dbl-buffered.
    __shared__ alignas(16) float e_sh[2][64 * kT];
    __shared__ alignas(16) float p_sh[64];
    __shared__ alignas(16) float ea_sh[64];
    const float4* p4 = (const float4*)p_sh;
    const float4* q4 = (const float4*)ea_sh;

    const float* fbase = feats + (size_t)b * kS * kT;   // this chain's rows
    const int*   mb    = mask  + (size_t)b * kS;

    // Issue the first 64-row stage EARLY; latency hides under TQ/EV init.
    // 12 calls x (64 lanes x 16B) = 12KB = rows 0..63 (contiguous).
#define STAGE_E(BUFIDX, T0) \
    _Pragma("unroll") \
    for (int c_ = 0; c_ < 12; ++c_) { \
        __builtin_amdgcn_global_load_lds( \
            (const __attribute__((address_space(1))) unsigned int*) \
                (fbase + (size_t)(T0) * kT + c_ * 256 + lane * 4), \
            (__attribute__((address_space(3))) unsigned int*) \
                (&e_sh[BUFIDX][c_ * 256]), \
            16, 0, 0); \
    }

    STAGE_E(0, 0)

    // T column and E column in registers.
    REP12(DECL_TQ)
    REP12(INIT_TQ)
    REP24(DECL_EV)
    REP24(INIT_EV)
    REP12(DECL_F)

    // part0 = emit[0] + transition[T-2, :]   (row 46, column j)
    float part = fbase[j] + trans[(kT - 2) * kT + j];
    p_sh[lane] = part;
    wave_fence();     // order p_sh write before gather reads
    REP12(LOADF)      // prefetch gathered part; valid until next p_sh write

    int mreg = mb[lane];   // mask words for steps 0..63 (coalesced)
    int buf  = 0;

    for (int blk = 0; blk < 16; ++blk) {
        // Drain staging: e_sh[buf] + mreg were issued ~64 steps ago (or at
        // init) -> this wait is effectively free.
        asm volatile("s_waitcnt vmcnt(0)" ::: "memory");

        // Uniform 64-step mask bitmask in an SGPR pair; per-step gate is
        // s_and/s_lshr + s_cbranch -- zero memory, zero VALU.
        unsigned long long bits = __ballot(mreg != 0);
        if (blk < 15) {
            mreg = mb[(blk + 1) * 64 + lane];   // next block's mask word
            STAGE_E(buf ^ 1, (blk + 1) * 64)    // next block's emission rows
        }
        int t = blk * 64;
        const int tend = t + 64;
        if (blk == 0) { bits >>= 1; t = 1; }  // scan starts at step 1

        for (; t < tend; ++t) {
            const bool mk = bits & 1ull;
            bits >>= 1;

            if (mk) {  // wave-uniform branch: skip masked-out steps
                // e from LDS; latency hides under pass1 (first use is ea).
                const float e = e_sh[buf][(t & 63) * kT + j];
                const float pe = part - e;  // off the M-critical path

                // pass 1 on prefetched F: M_j = max_i (T[i,j] + part_i)
                v2 mv0 = {-INFINITY, -INFINITY};
                v2 mv1 = mv0, mv2 = mv0, mv3 = mv0;
                REPQ(PASS1)
                mv0 = __builtin_elementwise_max(mv0, mv1);
                mv2 = __builtin_elementwise_max(mv2, mv3);
                mv0 = __builtin_elementwise_max(mv0, mv2);
                const float M = fmaxf(mv0.x, mv0.y);

                // lane i publishes ea_i = exp(part_i - e_i - M_i)
                const float ea = __expf(pe - M);
                wave_fence();          // order prior LDS reads before write
                ea_sh[lane] = ea;
                wave_fence();          // write precedes LOADQ reads

                // pass 2: S_j = sum_i exp(T[i,j]) * ea_i   (pk_fma chain)
                REP12(LOADQ)
                v2 sv0 = {0.f, 0.f};
                v2 sv1 = sv0, sv2 = sv0, sv3 = sv0;
                REPQ(PASS2)
                sv0 = sv0 + sv1;
                sv2 = sv2 + sv3;
                sv0 = sv0 + sv2;
                const float Ssum = sv0.x + sv0.y;

                part = 2.0f * e + M + __logf(Ssum);

                // publish part and refresh the gather; refreshed F stays
                // valid across masked steps (part unchanged there).
                wave_fence();          // prior F/Q reads precede overwrite
                p_sh[lane] = part;
                wave_fence();          // write precedes gather reads
                REP12(LOADF)
            }
        }
        buf ^= 1;
    }

    // Final transition-only step; only end_value[:, T-1] is stored.
    // F regs hold the current gathered part (prefetch invariant).
    {
        v2 mv0 = {-INFINITY, -INFINITY};
        v2 mv1 = mv0, mv2 = mv0, mv3 = mv0;
        REPQ(PASS1)
        mv0 = __builtin_elementwise_max(mv0, mv1);
        mv2 = __builtin_elementwise_max(mv2, mv3);
        mv0 = __builtin_elementwise_max(mv0, mv2);
        const float M = fmaxf(mv0.x, mv0.y);
        const float ea = __expf(part - M);   // no emission in final step
        wave_fence();
        ea_sh[lane] = ea;
        wave_fence();

        REP12(LOADQ)
        v2 sv0 = {0.f, 0.f};
        v2 sv1 = sv0, sv2 = sv0, sv3 = sv0;
        REPQ(PASS2)
        sv0 = sv0 + sv1;
        sv2 = sv2 + sv3;
        sv0 = sv0 + sv2;
        const float Ssum = sv0.x + sv0.y;
        const float val = M + __logf(Ssum);
        if (lane == kT - 1) out[1 + b] = val;  // score[b] = end_value[b,-1]
    }
}

// out[0] = sum(score). Single wave; no barriers needed.
__global__ __launch_bounds__(64) void sum_scores(
    const float* __restrict__ sc, float* __restrict__ out)
{
    float s = 0.f;
    for (int i = (int)threadIdx.x; i < kB; i += 64) s += sc[i];
#pragma unroll
    for (int off = 32; off > 0; off >>= 1) s += __shfl_down(s, off);
    if (threadIdx.x == 0) out[0] = s;
}

extern "C" void kernel_launch(void* const* d_in, const int* in_sizes, int n_in,
                              void* d_out, int out_size, void* d_ws, size_t ws_size,
                              hipStream_t stream) {
    const float* feats = (const float*)d_in[0];
    const int*   mask  = (const int*)d_in[1];
    const float* trans = (const float*)d_in[2];
    float*       out   = (float*)d_out;

    crf_fwd<<<dim3(kB), dim3(64), 0, stream>>>(feats, mask, trans, out);
    sum_scores<<<dim3(1), dim3(64), 0, stream>>>(out + 1, out);
}

// Round 8
// 382.030 us; speedup vs baseline: 1.3843x; 1.0174x over previous
//
#include <hip/hip_runtime.h>
#include <math.h>

// CRF forward partition scan. B=512, S=1024, T=48.
//
// R17: R16 chassis minus all in-loop wave_fence() scheduling barriers.
// R16 post-mortem: 286us = ~955 cyc/exec-step: two LDS round trips ~530
// (structurally forced: the repo's quirky LSE couples M_i into ea_i ->
// two cross-lane exchanges per step, proven irreducible), issue ~205,
// trees/exp/log ~100, UNEXPLAINED ~120. Theory: the wave_fences force
// coarse lgkmcnt(0) drains + block cross-region scheduling. They are
// redundant for correctness: every ordering they enforce is a same-array
// RAW/WAR dependence (p_sh reads vs p_sh[lane] write; ea_sh likewise)
// that LLVM alias analysis already respects, and cross-lane visibility
// within one wave is guaranteed by the in-order LDS pipe. Removing them
// is a pure scheduling-freedom probe (zero instruction change).
//  - emission staging per 64-step block via global_load_lds w16,
//    double-buffered, one vmcnt(0) drain per 64 steps (R14, proven).
//  - T column (TQ) + exp(T) (EV) in registers (R11+, proven).
//  - pass2 via LDS ea-broadcast + packed fma (R16, proven).

constexpr int kB  = 512;
constexpr int kS  = 1024;
constexpr int kT  = 48;

typedef float v2 __attribute__((ext_vector_type(2)));
struct V2P { v2 lo, hi; };

#define REP12(X) X(0) X(1) X(2) X(3) X(4) X(5) X(6) X(7) X(8) X(9) X(10) X(11)

// X(k, i0, i1): EV pair k covers transition rows i0=2k, i1=2k+1
#define REP24(X) \
  X(0,0,1)    X(1,2,3)    X(2,4,5)    X(3,6,7) \
  X(4,8,9)    X(5,10,11)  X(6,12,13)  X(7,14,15) \
  X(8,16,17)  X(9,18,19)  X(10,20,21) X(11,22,23) \
  X(12,24,25) X(13,26,27) X(14,28,29) X(15,30,31) \
  X(16,32,33) X(17,34,35) X(18,36,37) X(19,38,39) \
  X(20,40,41) X(21,42,43) X(22,44,45) X(23,46,47)

// X(q, evA, evB, a, b): quad q (rows 4q..4q+3), EV pair ids, acc ids
#define REPQ(X) \
  X(0,0,1,0,3)    X(1,2,3,1,2)    X(2,4,5,2,1)    X(3,6,7,3,0) \
  X(4,8,9,0,3)    X(5,10,11,1,2)  X(6,12,13,2,1)  X(7,14,15,3,0) \
  X(8,16,17,0,3)  X(9,18,19,1,2)  X(10,20,21,2,1) X(11,22,23,3,0)

// Transition column j, rows 4q..4q+3, held in registers for the whole kernel.
#define DECL_TQ(q)  float4 TQ##q;
#define INIT_TQ(q)  { TQ##q.x = trans[(4*(q)+0)*kT + j]; \
                      TQ##q.y = trans[(4*(q)+1)*kT + j]; \
                      TQ##q.z = trans[(4*(q)+2)*kT + j]; \
                      TQ##q.w = trans[(4*(q)+3)*kT + j]; }

#define DECL_EV(k,i0,i1)  v2 EV##k;
#define INIT_EV(k,i0,i1)  EV##k = (v2){__expf(trans[(i0)*kT + j]), \
                                       __expf(trans[(i1)*kT + j])};

// Gathered part vector, prefetched into 12 float4 regs (48 VGPRs).
#define DECL_F(q)  float4 F##q;
#define LOADF(q)   F##q = p4[q];

// Gathered ea vector (12 float4 reads from ea_sh).
#define LOADQ(q)   const float4 Q##q = q4[q];

// pass 1 (packed, on prefetched F): mv[a]=max(mv[a],T.lo+p.lo); mv[b] .hi
#define PASS1(q,evA,evB,a,b) { \
    const V2P t_ = __builtin_bit_cast(V2P, TQ##q); \
    const V2P p_ = __builtin_bit_cast(V2P, F##q);  \
    mv##a = __builtin_elementwise_max(mv##a, t_.lo + p_.lo); \
    mv##b = __builtin_elementwise_max(mv##b, t_.hi + p_.hi); }

// pass 2 (packed fma on gathered Q): sv[a] += EV[evA]*q.lo; sv[b] += .hi
#define PASS2(q,evA,evB,a,b) { \
    const V2P q_ = __builtin_bit_cast(V2P, Q##q); \
    sv##a = __builtin_elementwise_fma(EV##evA, q_.lo, sv##a); \
    sv##b = __builtin_elementwise_fma(EV##evB, q_.hi, sv##b); }

__global__ __launch_bounds__(64, 1) void crf_fwd(
    const float* __restrict__ feats,   // [B, S, T] fp32
    const int*   __restrict__ mask,    // [B, S] int32 (bool)
    const float* __restrict__ trans,   // [T, T] fp32
    float*       __restrict__ out)     // [1 + B]; we write out[1+b]
{
    const int b    = blockIdx.x;
    const int lane = threadIdx.x;
    const int j    = (lane < kT) ? lane : (kT - 1);  // clamp idle lanes

    // Emission staging: 64 rows x 48 floats = 12KB per buffer, dbl-buffered.
    __shared__ alignas(16) float e_sh[2][64 * kT];
    __shared__ alignas(16) float p_sh[64];
    __shared__ alignas(16) float ea_sh[64];
    const float4* p4 = (const float4*)p_sh;
    const float4* q4 = (const float4*)ea_sh;

    const float* fbase = feats + (size_t)b * kS * kT;   // this chain's rows
    const int*   mb    = mask  + (size_t)b * kS;

    // Issue the first 64-row stage EARLY; latency hides under TQ/EV init.
    // 12 calls x (64 lanes x 16B) = 12KB = rows 0..63 (contiguous).
#define STAGE_E(BUFIDX, T0) \
    _Pragma("unroll") \
    for (int c_ = 0; c_ < 12; ++c_) { \
        __builtin_amdgcn_global_load_lds( \
            (const __attribute__((address_space(1))) unsigned int*) \
                (fbase + (size_t)(T0) * kT + c_ * 256 + lane * 4), \
            (__attribute__((address_space(3))) unsigned int*) \
                (&e_sh[BUFIDX][c_ * 256]), \
            16, 0, 0); \
    }

    STAGE_E(0, 0)

    // T column and E column in registers.
    REP12(DECL_TQ)
    REP12(INIT_TQ)
    REP24(DECL_EV)
    REP24(INIT_EV)
    REP12(DECL_F)

    // part0 = emit[0] + transition[T-2, :]   (row 46, column j)
    float part = fbase[j] + trans[(kT - 2) * kT + j];
    p_sh[lane] = part;
    REP12(LOADF)      // ordered after the store by same-array aliasing;
                      // valid until next p_sh write

    int mreg = mb[lane];   // mask words for steps 0..63 (coalesced)
    int buf  = 0;

    for (int blk = 0; blk < 16; ++blk) {
        // Drain staging: e_sh[buf] + mreg were issued ~64 steps ago (or at
        // init) -> this wait is effectively free.
        asm volatile("s_waitcnt vmcnt(0)" ::: "memory");

        // Uniform 64-step mask bitmask in an SGPR pair; per-step gate is
        // s_and/s_lshr + s_cbranch -- zero memory, zero VALU.
        unsigned long long bits = __ballot(mreg != 0);
        if (blk < 15) {
            mreg = mb[(blk + 1) * 64 + lane];   // next block's mask word
            STAGE_E(buf ^ 1, (blk + 1) * 64)    // next block's emission rows
        }
        int t = blk * 64;
        const int tend = t + 64;
        if (blk == 0) { bits >>= 1; t = 1; }  // scan starts at step 1

        for (; t < tend; ++t) {
            const bool mk = bits & 1ull;
            bits >>= 1;

            if (mk) {  // wave-uniform branch: skip masked-out steps
                // e from LDS; latency hides under pass1 (first use is ea).
                const float e = e_sh[buf][(t & 63) * kT + j];
                const float pe = part - e;  // off the M-critical path

                // pass 1 on prefetched F: M_j = max_i (T[i,j] + part_i)
                v2 mv0 = {-INFINITY, -INFINITY};
                v2 mv1 = mv0, mv2 = mv0, mv3 = mv0;
                REPQ(PASS1)
                mv0 = __builtin_elementwise_max(mv0, mv1);
                mv2 = __builtin_elementwise_max(mv2, mv3);
                mv0 = __builtin_elementwise_max(mv0, mv2);
                const float M = fmaxf(mv0.x, mv0.y);

                // lane i publishes ea_i = exp(part_i - e_i - M_i).
                // Ordering vs prior LOADQ reads of ea_sh: same-array WAR,
                // respected by the compiler; HW LDS pipe is in-order.
                const float ea = __expf(pe - M);
                ea_sh[lane] = ea;

                // pass 2: S_j = sum_i exp(T[i,j]) * ea_i   (pk_fma chain)
                REP12(LOADQ)
                v2 sv0 = {0.f, 0.f};
                v2 sv1 = sv0, sv2 = sv0, sv3 = sv0;
                REPQ(PASS2)
                sv0 = sv0 + sv1;
                sv2 = sv2 + sv3;
                sv0 = sv0 + sv2;
                const float Ssum = sv0.x + sv0.y;

                part = 2.0f * e + M + __logf(Ssum);

                // publish part (ordered after LOADF reads by same-array
                // WAR) and refresh the gather; refreshed F stays valid
                // across masked steps (part unchanged there).
                p_sh[lane] = part;
                REP12(LOADF)
            }
        }
        buf ^= 1;
    }

    // Final transition-only step; only end_value[:, T-1] is stored.
    // F regs hold the current gathered part (prefetch invariant).
    {
        v2 mv0 = {-INFINITY, -INFINITY};
        v2 mv1 = mv0, mv2 = mv0, mv3 = mv0;
        REPQ(PASS1)
        mv0 = __builtin_elementwise_max(mv0, mv1);
        mv2 = __builtin_elementwise_max(mv2, mv3);
        mv0 = __builtin_elementwise_max(mv0, mv2);
        const float M = fmaxf(mv0.x, mv0.y);
        const float ea = __expf(part - M);   // no emission in final step
        ea_sh[lane] = ea;

        REP12(LOADQ)
        v2 sv0 = {0.f, 0.f};
        v2 sv1 = sv0, sv2 = sv0, sv3 = sv0;
        REPQ(PASS2)
        sv0 = sv0 + sv1;
        sv2 = sv2 + sv3;
        sv0 = sv0 + sv2;
        const float Ssum = sv0.x + sv0.y;
        const float val = M + __logf(Ssum);
        if (lane == kT - 1) out[1 + b] = val;  // score[b] = end_value[b,-1]
    }
}

// out[0] = sum(score). Single wave; no barriers needed.
__global__ __launch_bounds__(64) void sum_scores(
    const float* __restrict__ sc, float* __restrict__ out)
{
    float s = 0.f;
    for (int i = (int)threadIdx.x; i < kB; i += 64) s += sc[i];
#pragma unroll
    for (int off = 32; off > 0; off >>= 1) s += __shfl_down(s, off);
    if (threadIdx.x == 0) out[0] = s;
}

extern "C" void kernel_launch(void* const* d_in, const int* in_sizes, int n_in,
                              void* d_out, int out_size, void* d_ws, size_t ws_size,
                              hipStream_t stream) {
    const float* feats = (const float*)d_in[0];
    const int*   mask  = (const int*)d_in[1];
    const float* trans = (const float*)d_in[2];
    float*       out   = (float*)d_out;

    crf_fwd<<<dim3(kB), dim3(64), 0, stream>>>(feats, mask, trans, out);
    sum_scores<<<dim3(1), dim3(64), 0, stream>>>(out + 1, out);
}

// Round 9
// 377.404 us; speedup vs baseline: 1.4013x; 1.0123x over previous
//
#include <hip/hip_runtime.h>
#include <math.h>

// CRF forward partition scan. B=512, S=1024, T=48.
//
// R18: issue-shave + compaction on the R17 chassis. R17 post-mortem:
// 928 cyc/exec-step, issue 207, stall ~720 (2 LDS RTs ~360 + chains
// ~130 + slop). Structural options re-derived and killed: chain pairing
// (wall = iters_pair x t_pair, t_pair >= t_single, iters_pair > 717 ->
// guaranteed loss vs free different-SIMD concurrency) and parallel scan
// (repo's quirky LSE subtracts m_i not m_j -> non-associative -> scan
// would change the function). Remaining lever: cut issued work/crit path
// bit-exactly:
//  - mask compaction: while(bits){idx=ctz;...} -- no masked iterations,
//    no per-step branch.
//  - first-touch init: quads 0/1 ASSIGN (t+p / EV*q via pk_mul) instead
//    of max(-inf,..)/fma(..,0): bit-identical, ~24 fewer ops/step.
//  - max3 merge for M (max is exactly reassociative; no NaNs here).
//  - 2e+M hoisted ahead of the ea round trip.
//  - emission staging via global_load_lds w16, dbl-buffered (R14);
//    TQ/EV in regs (R11+); LDS broadcasts both passes (R16); no fences
//    (R17).

constexpr int kB  = 512;
constexpr int kS  = 1024;
constexpr int kT  = 48;

typedef float v2 __attribute__((ext_vector_type(2)));
struct V2P { v2 lo, hi; };

#define REP12(X) X(0) X(1) X(2) X(3) X(4) X(5) X(6) X(7) X(8) X(9) X(10) X(11)

// X(k, i0, i1): EV pair k covers transition rows i0=2k, i1=2k+1
#define REP24(X) \
  X(0,0,1)    X(1,2,3)    X(2,4,5)    X(3,6,7) \
  X(4,8,9)    X(5,10,11)  X(6,12,13)  X(7,14,15) \
  X(8,16,17)  X(9,18,19)  X(10,20,21) X(11,22,23) \
  X(12,24,25) X(13,26,27) X(14,28,29) X(15,30,31) \
  X(16,32,33) X(17,34,35) X(18,36,37) X(19,38,39) \
  X(20,40,41) X(21,42,43) X(22,44,45) X(23,46,47)

// X(q, evA, evB, a, b): quad q (rows 4q..4q+3), EV pair ids, acc ids.
// Quads 0,1 are the first touch of all four accs (assign); 2..11 accumulate.
#define REPQ01(X) \
  X(0,0,1,0,3)    X(1,2,3,1,2)
#define REPQR(X) \
  X(2,4,5,2,1)    X(3,6,7,3,0) \
  X(4,8,9,0,3)    X(5,10,11,1,2)  X(6,12,13,2,1)  X(7,14,15,3,0) \
  X(8,16,17,0,3)  X(9,18,19,1,2)  X(10,20,21,2,1) X(11,22,23,3,0)

// Transition column j, rows 4q..4q+3, held in registers for the whole kernel.
#define DECL_TQ(q)  float4 TQ##q;
#define INIT_TQ(q)  { TQ##q.x = trans[(4*(q)+0)*kT + j]; \
                      TQ##q.y = trans[(4*(q)+1)*kT + j]; \
                      TQ##q.z = trans[(4*(q)+2)*kT + j]; \
                      TQ##q.w = trans[(4*(q)+3)*kT + j]; }

#define DECL_EV(k,i0,i1)  v2 EV##k;
#define INIT_EV(k,i0,i1)  EV##k = (v2){__expf(trans[(i0)*kT + j]), \
                                       __expf(trans[(i1)*kT + j])};

// Gathered part vector, prefetched into 12 float4 regs (48 VGPRs).
#define DECL_F(q)  float4 F##q;
#define LOADF(q)   F##q = p4[q];

// Gathered ea vector (12 float4 reads from ea_sh).
#define LOADQ(q)   const float4 Q##q = q4[q];

// pass 1: first-touch assign (bit-identical to max(-inf, t+p)).
#define PASS1I(q,evA,evB,a,b) { \
    const V2P t_ = __builtin_bit_cast(V2P, TQ##q); \
    const V2P p_ = __builtin_bit_cast(V2P, F##q);  \
    mv##a = t_.lo + p_.lo; \
    mv##b = t_.hi + p_.hi; }
// pass 1: accumulate.
#define PASS1(q,evA,evB,a,b) { \
    const V2P t_ = __builtin_bit_cast(V2P, TQ##q); \
    const V2P p_ = __builtin_bit_cast(V2P, F##q);  \
    mv##a = __builtin_elementwise_max(mv##a, t_.lo + p_.lo); \
    mv##b = __builtin_elementwise_max(mv##b, t_.hi + p_.hi); }

// pass 2: first-touch assign via pk_mul (bit-identical to fma(..,0)).
#define PASS2I(q,evA,evB,a,b) { \
    const V2P q_ = __builtin_bit_cast(V2P, Q##q); \
    sv##a = EV##evA * q_.lo; \
    sv##b = EV##evB * q_.hi; }
// pass 2: accumulate (pk_fma).
#define PASS2(q,evA,evB,a,b) { \
    const V2P q_ = __builtin_bit_cast(V2P, Q##q); \
    sv##a = __builtin_elementwise_fma(EV##evA, q_.lo, sv##a); \
    sv##b = __builtin_elementwise_fma(EV##evB, q_.hi, sv##b); }

// 8-way max, depth 2 (max is exactly reassociative here: no NaNs, and
// any +-0 ambiguity is value-neutral through exp/add downstream).
__device__ __forceinline__ float max8(v2 a, v2 b, v2 c, v2 d) {
    const float t1 = fmaxf(fmaxf(a.x, a.y), b.x);
    const float t2 = fmaxf(fmaxf(b.y, c.x), c.y);
    const float t3 = fmaxf(d.x, d.y);
    return fmaxf(fmaxf(t1, t2), t3);
}

__global__ __launch_bounds__(64, 1) void crf_fwd(
    const float* __restrict__ feats,   // [B, S, T] fp32
    const int*   __restrict__ mask,    // [B, S] int32 (bool)
    const float* __restrict__ trans,   // [T, T] fp32
    float*       __restrict__ out)     // [1 + B]; we write out[1+b]
{
    const int b    = blockIdx.x;
    const int lane = threadIdx.x;
    const int j    = (lane < kT) ? lane : (kT - 1);  // clamp idle lanes

    // Emission staging: 64 rows x 48 floats = 12KB per buffer, dbl-buffered.
    __shared__ alignas(16) float e_sh[2][64 * kT];
    __shared__ alignas(16) float p_sh[64];
    __shared__ alignas(16) float ea_sh[64];
    const float4* p4 = (const float4*)p_sh;
    const float4* q4 = (const float4*)ea_sh;

    const float* fbase = feats + (size_t)b * kS * kT;   // this chain's rows
    const int*   mb    = mask  + (size_t)b * kS;

    // Issue the first 64-row stage EARLY; latency hides under TQ/EV init.
    // 12 calls x (64 lanes x 16B) = 12KB = rows 0..63 (contiguous).
#define STAGE_E(BUFIDX, T0) \
    _Pragma("unroll") \
    for (int c_ = 0; c_ < 12; ++c_) { \
        __builtin_amdgcn_global_load_lds( \
            (const __attribute__((address_space(1))) unsigned int*) \
                (fbase + (size_t)(T0) * kT + c_ * 256 + lane * 4), \
            (__attribute__((address_space(3))) unsigned int*) \
                (&e_sh[BUFIDX][c_ * 256]), \
            16, 0, 0); \
    }

    STAGE_E(0, 0)

    // T column and E column in registers.
    REP12(DECL_TQ)
    REP12(INIT_TQ)
    REP24(DECL_EV)
    REP24(INIT_EV)
    REP12(DECL_F)

    // part0 = emit[0] + transition[T-2, :]   (row 46, column j)
    float part = fbase[j] + trans[(kT - 2) * kT + j];
    p_sh[lane] = part;
    REP12(LOADF)      // ordered after the store by same-array aliasing;
                      // valid until next p_sh write

    int mreg = mb[lane];   // mask words for steps 0..63 (coalesced)
    int buf  = 0;

    for (int blk = 0; blk < 16; ++blk) {
        // Drain staging: e_sh[buf] + mreg were issued ~64 steps ago (or at
        // init) -> this wait is effectively free.
        asm volatile("s_waitcnt vmcnt(0)" ::: "memory");

        // Uniform 64-step mask bitmask in an SGPR pair; compacted
        // iteration via ctz -- masked steps cost nothing at all.
        unsigned long long bits = __ballot(mreg != 0);
        if (blk == 0) bits &= ~1ull;            // scan starts at step 1
        if (blk < 15) {
            mreg = mb[(blk + 1) * 64 + lane];   // next block's mask word
            STAGE_E(buf ^ 1, (blk + 1) * 64)    // next block's emission rows
        }

        while (bits) {
            const int idx = (int)__builtin_ctzll(bits);  // SALU s_ff1
            bits &= bits - 1;

            // e from LDS; latency hides under pass1 (first use is ea).
            const float e = e_sh[buf][idx * kT + j];
            const float pe = part - e;  // off the M-critical path

            // pass 1 on prefetched F: M_j = max_i (T[i,j] + part_i)
            v2 mv0, mv1, mv2, mv3;
            REPQ01(PASS1I)
            REPQR(PASS1)
            const float M = max8(mv0, mv1, mv2, mv3);
            const float c2 = 2.0f * e + M;   // hoisted ahead of the ea RT

            // lane i publishes ea_i = exp(part_i - e_i - M_i).
            // Ordering vs prior LOADQ reads of ea_sh: same-array WAR,
            // respected by the compiler; HW LDS pipe is in-order.
            const float ea = __expf(pe - M);
            ea_sh[lane] = ea;

            // pass 2: S_j = sum_i exp(T[i,j]) * ea_i   (pk chain)
            REP12(LOADQ)
            v2 sv0, sv1, sv2, sv3;
            REPQ01(PASS2I)
            REPQR(PASS2)
            sv0 = sv0 + sv1;
            sv2 = sv2 + sv3;
            sv0 = sv0 + sv2;
            const float Ssum = sv0.x + sv0.y;

            part = c2 + __logf(Ssum);

            // publish part (ordered after LOADF reads by same-array WAR)
            // and refresh the gather; F stays valid across masked steps.
            p_sh[lane] = part;
            REP12(LOADF)
        }
        buf ^= 1;
    }

    // Final transition-only step; only end_value[:, T-1] is stored.
    // F regs hold the current gathered part (prefetch invariant).
    {
        v2 mv0, mv1, mv2, mv3;
        REPQ01(PASS1I)
        REPQR(PASS1)
        const float M = max8(mv0, mv1, mv2, mv3);
        const float ea = __expf(part - M);   // no emission in final step
        ea_sh[lane] = ea;

        REP12(LOADQ)
        v2 sv0, sv1, sv2, sv3;
        REPQ01(PASS2I)
        REPQR(PASS2)
        sv0 = sv0 + sv1;
        sv2 = sv2 + sv3;
        sv0 = sv0 + sv2;
        const float Ssum = sv0.x + sv0.y;
        const float val = M + __logf(Ssum);
        if (lane == kT - 1) out[1 + b] = val;  // score[b] = end_value[b,-1]
    }
}

// out[0] = sum(score). Single wave; no barriers needed.
__global__ __launch_bounds__(64) void sum_scores(
    const float* __restrict__ sc, float* __restrict__ out)
{
    float s = 0.f;
    for (int i = (int)threadIdx.x; i < kB; i += 64) s += sc[i];
#pragma unroll
    for (int off = 32; off > 0; off >>= 1) s += __shfl_down(s, off);
    if (threadIdx.x == 0) out[0] = s;
}

extern "C" void kernel_launch(void* const* d_in, const int* in_sizes, int n_in,
                              void* d_out, int out_size, void* d_ws, size_t ws_size,
                              hipStream_t stream) {
    const float* feats = (const float*)d_in[0];
    const int*   mask  = (const int*)d_in[1];
    const float* trans = (const float*)d_in[2];
    float*       out   = (float*)d_out;

    crf_fwd<<<dim3(kB), dim3(64), 0, stream>>>(feats, mask, trans, out);
    sum_scores<<<dim3(1), dim3(64), 0, stream>>>(out + 1, out);
}